// Round 8
// baseline (146.347 us; speedup 1.0000x reference)
//
#include <hip/hip_runtime.h>
#include <hip/hip_cooperative_groups.h>
#include <math.h>

// KANConv2D via bf16 MFMA 16x16x32, R8: ONE cooperative kernel.
// Phase A: all blocks cooperatively convert fp32 weights -> bf16 pre-swizzled
//          MFMA B-frag streams in d_ws (each block a 1/196 slice).
// Phase 1: stage bases + x-halo into LDS (overlaps other blocks' phase A).
// grid.sync() -> weights visible device-wide, then the R7-validated GEMM body.
//
// Grid 196 blocks (4 b x 7x7 tiles of 8x8 px, M=64), 512 thr = 8 waves:
//   wave = (mh 0..3: M-tile of 16 px) x (nh 0..1: 32 oc via 2 B-frags).
// Frag maps (validated R1/R6/R7): A: m=lane&15, k=(lane>>4)*8+j;
//   B: n=lane&15, same k;  C/D: col=lane&15=n, row=(lane>>4)*4+reg=m.
// LDS: sb[32][100][8] bases (51200 B) + sx[100][40] x-halo (8000 B) = 59200 B.

namespace cg = cooperative_groups;

typedef __attribute__((ext_vector_type(8))) short bf16x8;
typedef __attribute__((ext_vector_type(4))) float f32x4;

#define MFMA16(a, b, c) __builtin_amdgcn_mfma_f32_16x16x32_bf16((a), (b), (c), 0, 0, 0)

__device__ __forceinline__ unsigned short f2bf(float f) {
    unsigned u = __builtin_bit_cast(unsigned, f);
    u = (u + 0x7fffu + ((u >> 16) & 1u)) >> 16;   // RNE
    return (unsigned short)u;
}

__device__ __forceinline__ void eval_bases(float v, float bs[8]) {
    #pragma unroll
    for (int i = 0; i < 8; ++i) bs[i] = 0.0f;
    // knots: t_g = (g-3)*0.4 - 1, support [-2.2, 2.2)
    float t = (v + 2.2f) * 2.5f;
    if (t >= 0.0f && t < 11.0f) {
        int j = (int)t;
        if (j > 10) j = 10;
        float knot = (float)(j - 3) * 0.4f - 1.0f;
        float u  = (v - knot) * 2.5f;
        float um = 1.0f - u;
        float u2 = u * u, u3 = u2 * u;
        const float s6 = 1.0f / 6.0f;
        float w0 = um * um * um * s6;
        float w1 = (3.0f * u3 - 6.0f * u2 + 4.0f) * s6;
        float w2 = (-3.0f * u3 + 3.0f * u2 + 3.0f * u + 1.0f) * s6;
        float w3 = u3 * s6;
        int i0 = j - 3;
        if (i0 >= 0)               bs[i0]     = w0;
        if (i0 + 1 >= 0 && i0 < 7) bs[i0 + 1] = w1;
        if (i0 + 2 >= 0 && i0 < 6) bs[i0 + 2] = w2;
        if (i0 + 3 <= 7)           bs[i0 + 3] = w3;
    }
}

__global__ __launch_bounds__(512)
void kan_coop_kernel(const float* __restrict__ x,
                     const float* __restrict__ wb,
                     const float* __restrict__ ws,
                     const float* __restrict__ sc,
                     unsigned short* wst,          // d_ws: 147456 bf16
                     unsigned short* wbt,          // d_ws: 18432 bf16
                     float* __restrict__ out) {
    __shared__ unsigned short smem[29600];   // 59200 B
    unsigned short* sb = smem;               // [32][100][8] = 25600 ushorts
    unsigned short* sx = smem + 25600;       // [100][40]    =  4000 ushorts

    const int tid = threadIdx.x;
    const int bx  = blockIdx.x;              // 0..195

    // ---- phase A: cooperative weight convert+swizzle (1/196 slice each) ----
    // Spline (k=p*8+f): wst[((nq*72+S)*64+l)*8+j] = ws[(nq*16+(l&15))*2304 + S*32+(l>>4)*8+j]
    // Base (k'=tap*32+c): wbt[((nq*9+s)*64+l)*8+j] = wb[(nq*16+(l&15))*288 + ((l>>4)*8+j)*9 + s]
    for (int i = bx * 512 + tid; i < 165888; i += 196 * 512) {
        if (i < 147456) {
            int j = i & 7, l = (i >> 3) & 63, t = i >> 9;   // t 0..287
            int S = t % 72, nq = t / 72;
            int oc = nq * 16 + (l & 15);
            int k  = S * 32 + (l >> 4) * 8 + j;
            wst[i] = f2bf(ws[oc * 2304 + k]);
        } else {
            int i2 = i - 147456;
            int j = i2 & 7, l = (i2 >> 3) & 63, t = i2 >> 9;  // t 0..35
            int s = t % 9, nq = t / 9;
            int oc = nq * 16 + (l & 15);
            int c  = (l >> 4) * 8 + j;
            wbt[i2] = f2bf(wb[oc * 288 + c * 9 + s]);
        }
    }
    __threadfence();   // make weight stores device-visible before grid sync

    const int b   = bx / 49;
    const int r   = bx - b * 49;
    const int ty  = r / 7;
    const int tx  = r - ty * 7;
    const int h0  = ty * 8, w0 = tx * 8;

    const int lane = tid & 63;
    const int wv   = tid >> 6;        // 0..7
    const int mh   = wv & 3;          // M-tile of 16 pixels
    const int nh   = wv >> 2;         // oc half (32 oc via 2 B-frags)
    const int ml   = lane & 15;       // A row within tile / B,C col
    const int kg   = lane >> 4;       // k-group 0..3 within k32 step
    const int p    = mh * 16 + ml;    // A-side pixel 0..63
    const int py0  = p >> 3, px0 = p & 7;

    // ---- phase 1: 32 ch x 10x10 halo: load x, eval bases, fill sb + sx ----
    float vv[7];
    #pragma unroll
    for (int j = 0; j < 7; ++j) {
        int i = tid + j * 512;        // 0..3583
        float val = 0.0f;
        if (i < 3200) {
            int c  = i / 100;
            int hp = i - c * 100;
            int hy = hp / 10;
            int hx = hp - hy * 10;
            int hh = h0 + hy - 1, ww = w0 + hx - 1;
            if ((unsigned)hh < 56u && (unsigned)ww < 56u)
                val = x[((b * 32 + c) * 56 + hh) * 56 + ww];
        }
        vv[j] = val;
    }
    #pragma unroll
    for (int j = 0; j < 7; ++j) {
        int i = tid + j * 512;
        if (i < 3200) {
            int c  = i / 100;
            int hp = i - c * 100;
            float bs[8];
            eval_bases(vv[j], bs);
            bf16x8 pk;
            #pragma unroll
            for (int j2 = 0; j2 < 8; ++j2) pk[j2] = (short)f2bf(bs[j2]);
            *reinterpret_cast<bf16x8*>(&sb[i * 8]) = pk;
            sx[hp * 40 + c] = f2bf(vv[j]);
        }
    }

    // ---- grid-wide sync: weights ready everywhere (also block barrier) ----
    cg::this_grid().sync();

    // spline A offsets (ushort units): step s = 9g+u reads patch p4 = 4s+kg
    //   -> c = 4g + (4u+kg)/9, tap = (4u+kg)%9, cell = (py0+kh)*10 + px0+kw
    int aoff[9];
    #pragma unroll
    for (int u = 0; u < 9; ++u) {
        int tt  = 4 * u + kg;         // 0..35
        int dc  = tt / 9;
        int tap = tt - dc * 9;
        int kh  = tap / 3;
        int kw  = tap - kh * 3;
        aoff[u] = (dc * 100 + (py0 + kh) * 10 + (px0 + kw)) * 8;
    }

    f32x4 accS0 = {0.f,0.f,0.f,0.f}, accS1 = {0.f,0.f,0.f,0.f};
    f32x4 accB0 = {0.f,0.f,0.f,0.f}, accB1 = {0.f,0.f,0.f,0.f};

    // ---- spline GEMM: 72 k32-steps, 2 B-frags (32 oc) per A-frag ----
    const unsigned short* bp0 = wst + (nh * 2) * 72 * 512 + lane * 8;
    const unsigned short* bp1 = bp0 + 72 * 512;
    int cbase = 0;
    for (int g = 0; g < 8; ++g) {
        #pragma unroll
        for (int u = 0; u < 9; ++u) {
            bf16x8 a   = *reinterpret_cast<const bf16x8*>(&sb[cbase + aoff[u]]);
            bf16x8 bw0 = *reinterpret_cast<const bf16x8*>(bp0 + (g * 9 + u) * 512);
            bf16x8 bw1 = *reinterpret_cast<const bf16x8*>(bp1 + (g * 9 + u) * 512);
            accS0 = MFMA16(a, bw0, accS0);
            accS1 = MFMA16(a, bw1, accS1);
        }
        cbase += 3200;                // 4 channels * 100 cells * 8
    }

    // ---- base GEMM: 9 k32-steps; step s = tap, lane reads c = kg*8..kg*8+7 ----
    {
        const unsigned short* bbp0 = wbt + (nh * 2) * 9 * 512 + lane * 8;
        const unsigned short* bbp1 = bbp0 + 9 * 512;
        #pragma unroll
        for (int s = 0; s < 9; ++s) {
            int kh = s / 3, kw = s - kh * 3;
            int cell = (py0 + kh) * 10 + (px0 + kw);
            bf16x8 a   = *reinterpret_cast<const bf16x8*>(&sx[cell * 40 + kg * 8]);
            bf16x8 bw0 = *reinterpret_cast<const bf16x8*>(bbp0 + s * 512);
            bf16x8 bw1 = *reinterpret_cast<const bf16x8*>(bbp1 + s * 512);
            accB0 = MFMA16(a, bw0, accB0);
            accB1 = MFMA16(a, bw1, accB1);
        }
    }

    // ---- epilogue: C/D row = kg*4+reg -> pixel pr = mh*16+kg*4+reg ----
    const int py  = mh * 2 + (kg >> 1);
    const int pxb = (kg & 1) * 4;
    #pragma unroll
    for (int t16 = 0; t16 < 2; ++t16) {
        const int oc = nh * 32 + t16 * 16 + ml;
        const float scv = sc[oc];
        const f32x4 aS = t16 ? accS1 : accS0;
        const f32x4 aB = t16 ? accB1 : accB0;
        f32x4 res;
        #pragma unroll
        for (int reg = 0; reg < 4; ++reg) {
            float bv = aB[reg];
            float si = bv / (1.0f + __expf(-bv));
            res[reg] = si + scv * aS[reg];
        }
        float* ob = out + ((b * 64 + oc) * 56 + h0 + py) * 56 + w0 + pxb;
        *reinterpret_cast<f32x4*>(ob) = res;
    }
}

extern "C" void kernel_launch(void* const* d_in, const int* in_sizes, int n_in,
                              void* d_out, int out_size, void* d_ws, size_t ws_size,
                              hipStream_t stream) {
    const float* x  = (const float*)d_in[0];   // (4,32,56,56)
    const float* wb = (const float*)d_in[1];   // (64,32,3,3)
    const float* ws = (const float*)d_in[2];   // (64,288,8)
    const float* sc = (const float*)d_in[3];   // (64,)
    float* out = (float*)d_out;                // (4,64,56,56)

    unsigned short* wst = (unsigned short*)d_ws;   // 147456 bf16
    unsigned short* wbt = wst + 147456;            // 18432 bf16

    void* args[] = { (void*)&x, (void*)&wb, (void*)&ws, (void*)&sc,
                     (void*)&wst, (void*)&wbt, (void*)&out };
    hipLaunchCooperativeKernel((const void*)kan_coop_kernel,
                               dim3(196), dim3(512), args, 0, stream);
}

// Round 9
// 78.429 us; speedup vs baseline: 1.8660x; 1.8660x over previous
//
#include <hip/hip_runtime.h>
#include <math.h>

// KANConv2D via bf16 MFMA 16x16x32 — R9 = R6 verbatim (best measured: 78.107 us).
// Rationale: R3/R4/R6/R7 (four structurally distinct mains) all land 78-80 us;
// dur_us is dominated by harness-fixed memory-bound fills (268 MB d_ws poison
// at ~83% HBM peak) + restore dispatches. R6 is the best-measured point.
// - cvt kernel pre-swizzles fp32 weights -> bf16 MFMA B-frag streams in d_ws.
// - Main: 392 blocks (4 b x 14x7 tiles of 4x8 px, M=32), 512 thr = 8 waves:
//   wave = (nq 0..3: oc quarter of 16) x (mh 0..1: M half of 16 rows).
//   No K-split -> no cross-wave reduction, single barrier, acc = 4+4 VGPRs.
// Frag maps (validated R1/R6): A: m=lane&15, k=(lane>>4)*8+j;
//   B: n=lane&15, same k;  C/D: col=lane&15=n, row=(lane>>4)*4+reg=m.

typedef __attribute__((ext_vector_type(8))) short bf16x8;
typedef __attribute__((ext_vector_type(4))) float f32x4;

#define MFMA16(a, b, c) __builtin_amdgcn_mfma_f32_16x16x32_bf16((a), (b), (c), 0, 0, 0)

__device__ __forceinline__ unsigned short f2bf(float f) {
    unsigned u = __builtin_bit_cast(unsigned, f);
    u = (u + 0x7fffu + ((u >> 16) & 1u)) >> 16;   // RNE
    return (unsigned short)u;
}

__device__ __forceinline__ void eval_bases(float v, float bs[8]) {
    #pragma unroll
    for (int i = 0; i < 8; ++i) bs[i] = 0.0f;
    // knots: t_g = (g-3)*0.4 - 1, support [-2.2, 2.2)
    float t = (v + 2.2f) * 2.5f;
    if (t >= 0.0f && t < 11.0f) {
        int j = (int)t;
        if (j > 10) j = 10;
        float knot = (float)(j - 3) * 0.4f - 1.0f;
        float u  = (v - knot) * 2.5f;
        float um = 1.0f - u;
        float u2 = u * u, u3 = u2 * u;
        const float s6 = 1.0f / 6.0f;
        float w0 = um * um * um * s6;
        float w1 = (3.0f * u3 - 6.0f * u2 + 4.0f) * s6;
        float w2 = (-3.0f * u3 + 3.0f * u2 + 3.0f * u + 1.0f) * s6;
        float w3 = u3 * s6;
        int i0 = j - 3;
        if (i0 >= 0)               bs[i0]     = w0;
        if (i0 + 1 >= 0 && i0 < 7) bs[i0 + 1] = w1;
        if (i0 + 2 >= 0 && i0 < 6) bs[i0 + 2] = w2;
        if (i0 + 3 <= 7)           bs[i0 + 3] = w3;
    }
}

// ---- pre-kernel: fp32 weights -> bf16 B-frag streams (16x16x32 layout) ----
// wst[((nq*72 + S)*64 + lane)*8 + j] = ws[(nq*16 + (lane&15))*2304 + S*32 + (lane>>4)*8 + j]
// wbt[((nq*9  + s)*64 + lane)*8 + j] = wb[(nq*16 + (lane&15))*288  + s*32 + (lane>>4)*8 + j]
__global__ __launch_bounds__(256)
void cvt_swz_kernel(const float* __restrict__ ws, const float* __restrict__ wb,
                    unsigned short* __restrict__ wst, unsigned short* __restrict__ wbt) {
    int i = blockIdx.x * 256 + threadIdx.x;
    if (i < 147456) {
        int j = i & 7, l = (i >> 3) & 63, t = i >> 9;   // t 0..287
        int S = t % 72, nq = t / 72;
        int oc = nq * 16 + (l & 15);
        int k  = S * 32 + (l >> 4) * 8 + j;
        wst[i] = f2bf(ws[oc * 2304 + k]);
    } else {
        int i2 = i - 147456;
        if (i2 < 18432) {
            int j = i2 & 7, l = (i2 >> 3) & 63, t = i2 >> 9;  // t 0..35
            int s = t % 9, nq = t / 9;
            int oc = nq * 16 + (l & 15);
            int k  = s * 32 + (l >> 4) * 8 + j;
            wbt[i2] = f2bf(wb[oc * 288 + k]);
        }
    }
}

__global__ __launch_bounds__(512)
void kan_mfma_kernel(const float* __restrict__ x,
                     const float* __restrict__ sc,
                     const unsigned short* __restrict__ wst,
                     const unsigned short* __restrict__ wbt,
                     float* __restrict__ out) {
    __shared__ unsigned short smem[24832];   // 49664 B -> 3 blocks/CU (LDS cap)
    unsigned short* sb    = smem;            // [32][60][8] = 15360 ushorts
    unsigned short* patch = smem + 15360;    // [32][296]   = 9472 ushorts

    const int tid = threadIdx.x;
    const int bx  = blockIdx.x;              // 0..391
    const int b   = bx / 98;
    const int r   = bx - b * 98;
    const int ty  = r / 7;
    const int tx  = r - ty * 7;
    const int h0  = ty * 4, w0 = tx * 8;

    const int lane = tid & 63;
    const int wv   = tid >> 6;        // 0..7
    const int nq   = wv & 3;          // oc quarter (16 oc)
    const int mh   = wv >> 2;         // M half (16 rows)
    const int ml   = lane & 15;       // A row within half / B,C col (oc)
    const int kg   = lane >> 4;       // k-group 0..3 within k32 step
    const int m    = mh * 16 + ml;    // global pixel row 0..31
    const int py0  = m >> 3, px0 = m & 7;

    // ---- phase 1: batch 4 independent x loads, eval bases, store + scatter ----
    float vv[4];
    #pragma unroll
    for (int j = 0; j < 4; ++j) {
        int i = tid + j * 512;        // 0..2047
        float val = 0.0f;
        if (i < 1920) {
            int c  = i / 60;
            int hp = i - c * 60;
            int hy = hp / 10;
            int hx = hp - hy * 10;
            int hh = h0 + hy - 1, ww = w0 + hx - 1;
            if ((unsigned)hh < 56u && (unsigned)ww < 56u)
                val = x[((b * 32 + c) * 56 + hh) * 56 + ww];
        }
        vv[j] = val;
    }
    #pragma unroll
    for (int j = 0; j < 4; ++j) {
        int i = tid + j * 512;
        if (i < 1920) {
            int c  = i / 60;
            int hp = i - c * 60;
            int hy = hp / 10;
            int hx = hp - hy * 10;
            float bs[8];
            eval_bases(vv[j], bs);
            bf16x8 pk;
            #pragma unroll
            for (int j2 = 0; j2 < 8; ++j2) pk[j2] = (short)f2bf(bs[j2]);
            *reinterpret_cast<bf16x8*>(&sb[i * 8]) = pk;
            // scatter x into patch: halo (hy,hx) -> m=(hy-kh)*8+(hx-kw), k=c*9+kh*3+kw
            unsigned short xb = f2bf(vv[j]);
            #pragma unroll
            for (int kh = 0; kh < 3; ++kh) {
                int py = hy - kh;
                if ((unsigned)py < 4u) {
                    #pragma unroll
                    for (int kw = 0; kw < 3; ++kw) {
                        int px = hx - kw;
                        if ((unsigned)px < 8u)
                            patch[(py * 8 + px) * 296 + c * 9 + kh * 3 + kw] = xb;
                    }
                }
            }
        }
    }
    __syncthreads();

    // spline A offsets (ushort units): step s = 9g+u reads p = 4s + kg
    //   -> c = 4g + (4u+kg)/9, tap = (4u+kg)%9
    int aoff[9];
    #pragma unroll
    for (int u = 0; u < 9; ++u) {
        int tt  = 4 * u + kg;         // 0..35
        int dc  = tt / 9;
        int tap = tt - dc * 9;
        int kh  = tap / 3;
        int kw  = tap - kh * 3;
        aoff[u] = (dc * 60 + (py0 + kh) * 10 + (px0 + kw)) * 8;
    }

    f32x4 accS = {0.f, 0.f, 0.f, 0.f};
    f32x4 accB = {0.f, 0.f, 0.f, 0.f};

    // ---- spline GEMM: 72 k32-steps, full K per wave ----
    const unsigned short* bp = wst + (nq * 72 * 64 + lane) * 8;
    int cbase = 0;
    for (int g = 0; g < 8; ++g) {
        #pragma unroll
        for (int u = 0; u < 9; ++u) {
            bf16x8 a  = *reinterpret_cast<const bf16x8*>(&sb[cbase + aoff[u]]);
            bf16x8 bw = *reinterpret_cast<const bf16x8*>(bp + (g * 9 + u) * 512);
            accS = MFMA16(a, bw, accS);
        }
        cbase += 1920;                // 4 channels * 480 ushorts
    }

    // ---- base GEMM: 9 k32-steps ----
    {
        const unsigned short* ap  = patch + m * 296 + kg * 8;
        const unsigned short* bbp = wbt + (nq * 9 * 64 + lane) * 8;
        #pragma unroll
        for (int s = 0; s < 9; ++s) {
            bf16x8 a  = *reinterpret_cast<const bf16x8*>(ap + s * 32);
            bf16x8 bw = *reinterpret_cast<const bf16x8*>(bbp + s * 512);
            accB = MFMA16(a, bw, accB);
        }
    }

    // ---- epilogue: C/D row = (lane>>4)*4 + reg = pixel, col = ml = oc ----
    const int oc  = nq * 16 + ml;
    const float scv = sc[oc];
    const int rowb = mh * 16 + kg * 4;        // m of reg 0; regs span same py
    const int py   = rowb >> 3;
    const int pxb  = rowb & 7;                // 0 or 4
    float* ob = out + ((b * 64 + oc) * 56 + h0 + py) * 56 + w0 + pxb;
    f32x4 res;
    #pragma unroll
    for (int reg = 0; reg < 4; ++reg) {
        float bv = accB[reg];
        float si = bv / (1.0f + __expf(-bv));
        res[reg] = si + scv * accS[reg];
    }
    *reinterpret_cast<f32x4*>(ob) = res;
}

extern "C" void kernel_launch(void* const* d_in, const int* in_sizes, int n_in,
                              void* d_out, int out_size, void* d_ws, size_t ws_size,
                              hipStream_t stream) {
    const float* x  = (const float*)d_in[0];   // (4,32,56,56)
    const float* wb = (const float*)d_in[1];   // (64,32,3,3)
    const float* ws = (const float*)d_in[2];   // (64,288,8)
    const float* sc = (const float*)d_in[3];   // (64,)
    float* out = (float*)d_out;                // (4,64,56,56)

    unsigned short* wst = (unsigned short*)d_ws;   // 147456 bf16
    unsigned short* wbt = wst + 147456;            // 18432 bf16

    cvt_swz_kernel<<<648, 256, 0, stream>>>(ws, wb, wst, wbt);
    kan_mfma_kernel<<<392, 512, 0, stream>>>(x, sc, wst, wbt, out);
}